// Round 6
// baseline (342.136 us; speedup 1.0000x reference)
//
#include <hip/hip_runtime.h>

typedef unsigned short ushort_t;
typedef __attribute__((ext_vector_type(8))) short bf16x8;     // 8 bf16 (4 VGPRs)
typedef __attribute__((ext_vector_type(4))) float f32x4;
typedef __attribute__((ext_vector_type(4))) unsigned short us4;

#define DM 2048
#define RK 64

__device__ __forceinline__ ushort_t f2b(float f) {
    union { float f; unsigned u; } x; x.f = f;
    unsigned r = x.u + 0x7fff + ((x.u >> 16) & 1);   // RNE
    return (ushort_t)(r >> 16);
}

// ---------------- P1: Mmid[64][64] = butterfly(Wbs) @ Wcr ----------------
__global__ void k_p1(const float* __restrict__ Wbs, const float* __restrict__ Af,
                     const float* __restrict__ Wcr, float* __restrict__ Mmid) {
    __shared__ float X[64 * 256];          // 64 KB, becomes T1
    const int tid = threadIdx.x;
#pragma unroll
    for (int i = 0; i < 16; ++i) {
        int e = (i * 256 + tid) * 4;
        *(float4*)&X[e] = *(const float4*)&Wbs[e];
    }
    __syncthreads();
#pragma unroll
    for (int l = 0; l < 8; ++l) {
        const int bit = 1 << (7 - l);
        const float a00 = Af[l * 4 + 0], a01 = Af[l * 4 + 1];
        const float a10 = Af[l * 4 + 2], a11 = Af[l * 4 + 3];
#pragma unroll 4
        for (int p = 0; p < 32; ++p) {
            int pid = p * 256 + tid;
            int row = pid >> 7;
            int off = pid & 127;
            int lo = off & (bit - 1);
            int n0 = ((off ^ lo) << 1) | lo;
            int n1 = n0 | bit;
            float x0 = X[row * 256 + n0], x1 = X[row * 256 + n1];
            X[row * 256 + n0] = x0 * a00 + x1 * a10;
            X[row * 256 + n1] = x0 * a01 + x1 * a11;
        }
        __syncthreads();
    }
    int g = blockIdx.x * 256 + tid;
    int r1 = g >> 6, r2 = g & 63;
    float s = 0.f;
#pragma unroll 8
    for (int n = 0; n < 256; ++n) s += X[r1 * 256 + n] * Wcr[n * 64 + r2];
    Mmid[g] = s;
}

// ---------------- P2: WeffT[64][2048] = (Wbr @ Mmid)^T, WcT[2048][64] = Wcm^T ----
__global__ void k_p2(const float* __restrict__ Wbr, const float* __restrict__ Mmid,
                     const float* __restrict__ Wcm,
                     ushort_t* __restrict__ WeffT, ushort_t* __restrict__ WcT) {
    const int b = blockIdx.x, tid = threadIdx.x;
    if (b < 32) {
        __shared__ float LW[64][65];
        __shared__ float LM[64 * 64];
#pragma unroll
        for (int i = 0; i < 4; ++i) {
            int e = (i * 256 + tid) * 4;
            int kk = e >> 6, r = e & 63;
            float4 v = *(const float4*)&Wbr[(size_t)b * 4096 + e];
            LW[kk][r] = v.x; LW[kk][r + 1] = v.y; LW[kk][r + 2] = v.z; LW[kk][r + 3] = v.w;
        }
#pragma unroll
        for (int i = 0; i < 4; ++i) {
            int e = (i * 256 + tid) * 4;
            *(float4*)&LM[e] = *(const float4*)&Mmid[e];
        }
        __syncthreads();
        int kk = tid & 63, n0 = (tid >> 6) * 16;
        float acc[16];
#pragma unroll
        for (int j = 0; j < 16; ++j) acc[j] = 0.f;
        for (int r = 0; r < 64; ++r) {
            float wv = LW[kk][r];
            const float* mrow = &LM[r * 64 + n0];
            float4 m0 = *(const float4*)(mrow);
            float4 m1 = *(const float4*)(mrow + 4);
            float4 m2 = *(const float4*)(mrow + 8);
            float4 m3 = *(const float4*)(mrow + 12);
            acc[0] += wv * m0.x; acc[1] += wv * m0.y; acc[2] += wv * m0.z; acc[3] += wv * m0.w;
            acc[4] += wv * m1.x; acc[5] += wv * m1.y; acc[6] += wv * m1.z; acc[7] += wv * m1.w;
            acc[8] += wv * m2.x; acc[9] += wv * m2.y; acc[10] += wv * m2.z; acc[11] += wv * m2.w;
            acc[12] += wv * m3.x; acc[13] += wv * m3.y; acc[14] += wv * m3.z; acc[15] += wv * m3.w;
        }
#pragma unroll
        for (int j = 0; j < 16; ++j)
            WeffT[(size_t)(n0 + j) * DM + b * 64 + kk] = f2b(acc[j]);
    } else {
        __shared__ float LT[64][65];
        const int n0 = (b - 32) * 64;
#pragma unroll
        for (int i = 0; i < 4; ++i) {
            int e = (i * 256 + tid) * 4;
            int k = e >> 6, nn = e & 63;
            float4 v = *(const float4*)&Wcm[(size_t)k * DM + n0 + nn];
            LT[k][nn] = v.x; LT[k][nn + 1] = v.y; LT[k][nn + 2] = v.z; LT[k][nn + 3] = v.w;
        }
        __syncthreads();
#pragma unroll
        for (int i = 0; i < 4; ++i) {
            int e = (i * 256 + tid) * 4;
            int nn = e >> 6, k = e & 63;
            us4 o;
            o.x = f2b(LT[k][nn]); o.y = f2b(LT[k + 1][nn]);
            o.z = f2b(LT[k + 2][nn]); o.w = f2b(LT[k + 3][nn]);
            *(us4*)&WcT[(size_t)(n0 + nn) * RK + k] = o;
        }
    }
}

// ---------------- A: t[16384][64] = u @ W_eff (bf16 out) ----------------
// 256 blocks x 4 waves, 64 rows/block. W_eff staged to LDS in 8 x 32KB
// K-slices via global_load_lds, SHARED by the 4 waves (table read once per
// 64 rows instead of once per 16 -> table traffic 268MB -> 64MB). Each wave
// keeps full-K accumulators for its own 16 rows (no K-split, no partials).
// LDS XOR-swizzle: 16B-chunk index ^= (n&7), applied to the global SOURCE of
// the DMA and to the ds_read address (both-sides rule).
__global__ __launch_bounds__(256) void k_a(const float* __restrict__ u,
                                           const ushort_t* __restrict__ WeffT,
                                           ushort_t* __restrict__ tg) {
    __shared__ ushort_t Wl[64 * 256];      // 32KB: one K-slice [64n][256k]; reused for t-transpose

    const int tid = threadIdx.x;
    const int w = tid >> 6;                // wave 0..3 -> rows w*16..+16
    const int lane = tid & 63;
    const int m16 = lane & 15;
    const int quad = lane >> 4;
    const size_t r0 = (size_t)blockIdx.x * 64;

    const float* ap = u + (r0 + w * 16 + m16) * DM + quad * 8;

    f32x4 acc[4];
#pragma unroll
    for (int j = 0; j < 4; ++j) acc[j] = (f32x4){0.f, 0.f, 0.f, 0.f};

    for (int s = 0; s < 8; ++s) {
        __syncthreads();                   // prev slice's reads done before overwrite
        // ---- stage slice s: wave w stages rows w*16..+16 (8 x 1KB DMA) ----
#pragma unroll
        for (int j = 0; j < 8; ++j) {
            int n = (w << 4) + j * 2 + (lane >> 5);
            int p = lane & 31;
            int chi = p ^ (n & 7);         // inverse-swizzled source chunk
            const ushort_t* gp = WeffT + (size_t)n * DM + s * 256 + chi * 8;
            __builtin_amdgcn_global_load_lds(
                (const __attribute__((address_space(1))) void*)gp,
                (__attribute__((address_space(3))) void*)&Wl[((w << 4) + j * 2) * 256],
                16, 0, 0);
        }
        __syncthreads();                   // drains vmcnt -> DMA complete for all waves

        // ---- compute: 8 chunks of K=32 ----
#pragma unroll
        for (int c = 0; c < 8; ++c) {
            float4 u0 = *(const float4*)(ap + s * 256 + c * 32);
            float4 u1 = *(const float4*)(ap + s * 256 + c * 32 + 4);
            bf16x8 a;
            a[0] = (short)f2b(u0.x); a[1] = (short)f2b(u0.y);
            a[2] = (short)f2b(u0.z); a[3] = (short)f2b(u0.w);
            a[4] = (short)f2b(u1.x); a[5] = (short)f2b(u1.y);
            a[6] = (short)f2b(u1.z); a[7] = (short)f2b(u1.w);
#pragma unroll
            for (int j = 0; j < 4; ++j) {
                int n = m16 + 16 * j;
                int chi = ((c << 2) | quad) ^ (n & 7);
                bf16x8 b = *(const bf16x8*)&Wl[n * 256 + chi * 8];
                acc[j] = __builtin_amdgcn_mfma_f32_16x16x32_bf16(a, b, acc[j], 0, 0, 0);
            }
        }
    }

    // ---- t transpose via LDS (reuse Wl) and bf16 store ----
    __syncthreads();
    ushort_t* tt = Wl;                     // [64 rows][stride 72]
#pragma unroll
    for (int j = 0; j < 4; ++j)
#pragma unroll
        for (int i = 0; i < 4; ++i)
            tt[((w << 4) + quad * 4 + i) * 72 + 16 * j + m16] = f2b(acc[j][i]);
    __syncthreads();
    {
        const int lr = (w << 4) + m16;     // local row 0..63
        bf16x8 t0 = *(const bf16x8*)&tt[lr * 72 + quad * 16];
        bf16x8 t1 = *(const bf16x8*)&tt[lr * 72 + quad * 16 + 8];
        ushort_t* tp = tg + (r0 + lr) * RK + quad * 16;
        *(bf16x8*)tp = t0;
        *(bf16x8*)(tp + 8) = t1;
    }
}

// ---------------- B: out = t @ W_c_model + D*u ----------------
// 1024 blocks x 1 wave; block = 256 rows x 128 cols. The 128-col WcT slice
// (16KB) is held STATIONARY in 16 register fragments and reused across 16
// row-groups (table traffic 268MB -> ~16MB). t/u/out are pure coalesced
// streams. MFMA operand arrangement replicated from the verified R2 phase 2.
__global__ __launch_bounds__(64) void k_b(const ushort_t* __restrict__ tg,
                                          const float* __restrict__ u,
                                          const ushort_t* __restrict__ WcT,
                                          const float* __restrict__ Dvec,
                                          float* __restrict__ out) {
    const int lane = threadIdx.x;
    const int m16 = lane & 15;
    const int quad = lane >> 4;
    const size_t r0 = (size_t)(blockIdx.x >> 4) * 256;
    const int c0 = (blockIdx.x & 15) * 128;

    // stationary WcT fragments + D fragments for this col-slice
    bf16x8 wb0[8], wb1[8];
    float4 dvv[8];
#pragma unroll
    for (int ct = 0; ct < 8; ++ct) {
        const ushort_t* p = WcT + (size_t)(c0 + ct * 16 + m16) * RK + quad * 8;
        wb0[ct] = *(const bf16x8*)(p);
        wb1[ct] = *(const bf16x8*)(p + 32);
        dvv[ct] = *(const float4*)(Dvec + c0 + ct * 16 + quad * 4);
    }

    for (int g = 0; g < 16; ++g) {
        const size_t rg = r0 + g * 16;
        const ushort_t* tp = tg + (rg + m16) * RK + quad * 8;
        bf16x8 ta0 = *(const bf16x8*)(tp);
        bf16x8 ta1 = *(const bf16x8*)(tp + 32);
        const float* up = u + (rg + m16) * DM + c0 + quad * 4;
        float* op = out + (rg + m16) * DM + c0 + quad * 4;
#pragma unroll
        for (int ct = 0; ct < 8; ++ct) {
            f32x4 o = {0.f, 0.f, 0.f, 0.f};
            // lane stores out[rg+m16][c0 + ct*16 + quad*4 + i]  -> float4
            o = __builtin_amdgcn_mfma_f32_16x16x32_bf16(wb0[ct], ta0, o, 0, 0, 0);
            o = __builtin_amdgcn_mfma_f32_16x16x32_bf16(wb1[ct], ta1, o, 0, 0, 0);
            float4 uv = *(const float4*)(up + ct * 16);
            f32x4 st;
            st[0] = o[0] + dvv[ct].x * uv.x;
            st[1] = o[1] + dvv[ct].y * uv.y;
            st[2] = o[2] + dvv[ct].z * uv.z;
            st[3] = o[3] + dvv[ct].w * uv.w;
            *(f32x4*)(op + ct * 16) = st;
        }
    }
}

extern "C" void kernel_launch(void* const* d_in, const int* in_sizes, int n_in,
                              void* d_out, int out_size, void* d_ws, size_t ws_size,
                              hipStream_t stream) {
    (void)in_sizes; (void)n_in; (void)out_size; (void)ws_size;
    const float* u   = (const float*)d_in[0];
    const float* Af  = (const float*)d_in[1];
    const float* Wbr = (const float*)d_in[2];
    const float* Wbs = (const float*)d_in[3];
    const float* Wcr = (const float*)d_in[4];
    const float* Wcm = (const float*)d_in[5];
    const float* Dv  = (const float*)d_in[6];
    float* out = (float*)d_out;

    char* ws = (char*)d_ws;
    float*    Mmid  = (float*)(ws + 0);            // 64*64*4    =   16384
    ushort_t* WeffT = (ushort_t*)(ws + 16384);     // 64*2048*2  =  262144
    ushort_t* WcT   = (ushort_t*)(ws + 278528);    // 2048*64*2  =  262144
    ushort_t* tg    = (ushort_t*)(ws + 540672);    // 16384*64*2 = 2097152

    k_p1<<<16, 256, 0, stream>>>(Wbs, Af, Wcr, Mmid);
    k_p2<<<64, 256, 0, stream>>>(Wbr, Mmid, Wcm, WeffT, WcT);
    k_a <<<256, 256, 0, stream>>>(u, WeffT, tg);
    k_b <<<1024, 64, 0, stream>>>(tg, u, WcT, Dv, out);
}

// Round 7
// 319.461 us; speedup vs baseline: 1.0710x; 1.0710x over previous
//
#include <hip/hip_runtime.h>

typedef unsigned short ushort_t;
typedef __attribute__((ext_vector_type(8))) short bf16x8;     // 8 bf16 (4 VGPRs)
typedef __attribute__((ext_vector_type(4))) float f32x4;
typedef __attribute__((ext_vector_type(4))) unsigned short us4;
typedef __attribute__((ext_vector_type(2))) unsigned short us2;

#define DM 2048
#define RK 64

__device__ __forceinline__ ushort_t f2b(float f) {
    union { float f; unsigned u; } x; x.f = f;
    unsigned r = x.u + 0x7fff + ((x.u >> 16) & 1);   // RNE
    return (ushort_t)(r >> 16);
}

// ---------------- P1: Mmid[64][64] = butterfly(Wbs) @ Wcr ----------------
__global__ void k_p1(const float* __restrict__ Wbs, const float* __restrict__ Af,
                     const float* __restrict__ Wcr, float* __restrict__ Mmid) {
    __shared__ float X[64 * 256];          // 64 KB, becomes T1
    const int tid = threadIdx.x;
#pragma unroll
    for (int i = 0; i < 16; ++i) {
        int e = (i * 256 + tid) * 4;
        *(float4*)&X[e] = *(const float4*)&Wbs[e];
    }
    __syncthreads();
#pragma unroll
    for (int l = 0; l < 8; ++l) {
        const int bit = 1 << (7 - l);
        const float a00 = Af[l * 4 + 0], a01 = Af[l * 4 + 1];
        const float a10 = Af[l * 4 + 2], a11 = Af[l * 4 + 3];
#pragma unroll 4
        for (int p = 0; p < 32; ++p) {
            int pid = p * 256 + tid;
            int row = pid >> 7;
            int off = pid & 127;
            int lo = off & (bit - 1);
            int n0 = ((off ^ lo) << 1) | lo;
            int n1 = n0 | bit;
            float x0 = X[row * 256 + n0], x1 = X[row * 256 + n1];
            X[row * 256 + n0] = x0 * a00 + x1 * a10;
            X[row * 256 + n1] = x0 * a01 + x1 * a11;
        }
        __syncthreads();
    }
    int g = blockIdx.x * 256 + tid;
    int r1 = g >> 6, r2 = g & 63;
    float s = 0.f;
#pragma unroll 8
    for (int n = 0; n < 256; ++n) s += X[r1 * 256 + n] * Wcr[n * 64 + r2];
    Mmid[g] = s;
}

// ---------------- P2: WeffT[64][2048] = (Wbr @ Mmid)^T, WcT[2048][64] = Wcm^T ----
__global__ void k_p2(const float* __restrict__ Wbr, const float* __restrict__ Mmid,
                     const float* __restrict__ Wcm,
                     ushort_t* __restrict__ WeffT, ushort_t* __restrict__ WcT) {
    const int b = blockIdx.x, tid = threadIdx.x;
    if (b < 32) {
        __shared__ float LW[64][65];
        __shared__ float LM[64 * 64];
#pragma unroll
        for (int i = 0; i < 4; ++i) {
            int e = (i * 256 + tid) * 4;
            int kk = e >> 6, r = e & 63;
            float4 v = *(const float4*)&Wbr[(size_t)b * 4096 + e];
            LW[kk][r] = v.x; LW[kk][r + 1] = v.y; LW[kk][r + 2] = v.z; LW[kk][r + 3] = v.w;
        }
#pragma unroll
        for (int i = 0; i < 4; ++i) {
            int e = (i * 256 + tid) * 4;
            *(float4*)&LM[e] = *(const float4*)&Mmid[e];
        }
        __syncthreads();
        int kk = tid & 63, n0 = (tid >> 6) * 16;
        float acc[16];
#pragma unroll
        for (int j = 0; j < 16; ++j) acc[j] = 0.f;
        for (int r = 0; r < 64; ++r) {
            float wv = LW[kk][r];
            const float* mrow = &LM[r * 64 + n0];
            float4 m0 = *(const float4*)(mrow);
            float4 m1 = *(const float4*)(mrow + 4);
            float4 m2 = *(const float4*)(mrow + 8);
            float4 m3 = *(const float4*)(mrow + 12);
            acc[0] += wv * m0.x; acc[1] += wv * m0.y; acc[2] += wv * m0.z; acc[3] += wv * m0.w;
            acc[4] += wv * m1.x; acc[5] += wv * m1.y; acc[6] += wv * m1.z; acc[7] += wv * m1.w;
            acc[8] += wv * m2.x; acc[9] += wv * m2.y; acc[10] += wv * m2.z; acc[11] += wv * m2.w;
            acc[12] += wv * m3.x; acc[13] += wv * m3.y; acc[14] += wv * m3.z; acc[15] += wv * m3.w;
        }
#pragma unroll
        for (int j = 0; j < 16; ++j)
            WeffT[(size_t)(n0 + j) * DM + b * 64 + kk] = f2b(acc[j]);
    } else {
        __shared__ float LT[64][65];
        const int n0 = (b - 32) * 64;
#pragma unroll
        for (int i = 0; i < 4; ++i) {
            int e = (i * 256 + tid) * 4;
            int k = e >> 6, nn = e & 63;
            float4 v = *(const float4*)&Wcm[(size_t)k * DM + n0 + nn];
            LT[k][nn] = v.x; LT[k][nn + 1] = v.y; LT[k][nn + 2] = v.z; LT[k][nn + 3] = v.w;
        }
        __syncthreads();
#pragma unroll
        for (int i = 0; i < 4; ++i) {
            int e = (i * 256 + tid) * 4;
            int nn = e >> 6, k = e & 63;
            us4 o;
            o.x = f2b(LT[k][nn]); o.y = f2b(LT[k + 1][nn]);
            o.z = f2b(LT[k + 2][nn]); o.w = f2b(LT[k + 3][nn]);
            *(us4*)&WcT[(size_t)(n0 + nn) * RK + k] = o;
        }
    }
}

// ---------------- A: t[16384][64] = u @ W_eff (bf16 out) ----------------
// WEIGHT-STATIONARY: 256 blocks x 8 waves x 64 rows. Wave w pins its K-slice
// [w*256,+256) x 64n of WeffT in 32 bf16x8 register fragments (128 VGPR),
// loaded ONCE. u streams straight from global into MFMAs -- no LDS staging,
// no DMA drains. Weight regs are loop-invariant: the compiler cannot sink
// them, so deep VGPR use is structurally forced. 2 light barriers per
// 16-row group for the f32 cross-wave reduce (padded [64][20], 2-way banks).
__global__ __launch_bounds__(512) void k_a(const float* __restrict__ u,
                                           const ushort_t* __restrict__ WeffT,
                                           ushort_t* __restrict__ tg) {
    __shared__ float red[8][64][20];       // 40 KB partial-t, [wave][n][r]

    const int tid = threadIdx.x;
    const int w = tid >> 6;                // wave 0..7 -> K-slice [w*256,+256)
    const int lane = tid & 63;
    const int m16 = lane & 15;
    const int quad = lane >> 4;
    const size_t r0 = (size_t)blockIdx.x * 64;

    // ---- preload stationary weight fragments (32 x 16B, L2-resident) ----
    bf16x8 Wf[8][4];
    {
        const ushort_t* wbase = WeffT + (size_t)m16 * DM + w * 256 + quad * 8;
#pragma unroll
        for (int c = 0; c < 8; ++c)
#pragma unroll
            for (int j = 0; j < 4; ++j)
                Wf[c][j] = *(const bf16x8*)(wbase + (size_t)j * 16 * DM + c * 32);
    }

    for (int g = 0; g < 4; ++g) {
        const float* ap = u + (r0 + g * 16 + m16) * DM + w * 256 + quad * 8;
        f32x4 acc[4];
#pragma unroll
        for (int j = 0; j < 4; ++j) acc[j] = (f32x4){0.f, 0.f, 0.f, 0.f};

#pragma unroll
        for (int c = 0; c < 8; ++c) {
            float4 u0 = *(const float4*)(ap + c * 32);
            float4 u1 = *(const float4*)(ap + c * 32 + 4);
            bf16x8 a;
            a[0] = (short)f2b(u0.x); a[1] = (short)f2b(u0.y);
            a[2] = (short)f2b(u0.z); a[3] = (short)f2b(u0.w);
            a[4] = (short)f2b(u1.x); a[5] = (short)f2b(u1.y);
            a[6] = (short)f2b(u1.z); a[7] = (short)f2b(u1.w);
#pragma unroll
            for (int j = 0; j < 4; ++j)
                acc[j] = __builtin_amdgcn_mfma_f32_16x16x32_bf16(a, Wf[c][j], acc[j], 0, 0, 0);
        }

        // partial t: acc[j][i] = t[r = quad*4+i][n = 16j+m16]
#pragma unroll
        for (int j = 0; j < 4; ++j)
            *(f32x4*)&red[w][16 * j + m16][quad * 4] = acc[j];
        __syncthreads();

        // reduce 1024 entries / 512 threads = 2 each; coalesced bf16 store
        {
            const int r = tid >> 5;             // 0..15
            const int n0 = (tid & 31) * 2;      // 0..62 even
            float s0 = 0.f, s1 = 0.f;
#pragma unroll
            for (int ww = 0; ww < 8; ++ww) {
                s0 += red[ww][n0][r];
                s1 += red[ww][n0 + 1][r];
            }
            us2 o; o.x = f2b(s0); o.y = f2b(s1);
            *(us2*)&tg[(r0 + g * 16 + r) * RK + n0] = o;
        }
        __syncthreads();                        // before next group overwrites red
    }
}

// ---------------- B: out = t @ W_c_model + D*u ----------------
// 2048 blocks x 1 wave; block = 128 rows x 128 cols (8 blocks/CU for TLP).
// The 128-col WcT slice (16KB) is held STATIONARY in 16 register fragments
// and reused across 8 row-groups. t/u/out are pure coalesced streams.
// MFMA operand arrangement replicated from the verified R2 phase 2.
__global__ __launch_bounds__(64) void k_b(const ushort_t* __restrict__ tg,
                                          const float* __restrict__ u,
                                          const ushort_t* __restrict__ WcT,
                                          const float* __restrict__ Dvec,
                                          float* __restrict__ out) {
    const int lane = threadIdx.x;
    const int m16 = lane & 15;
    const int quad = lane >> 4;
    const size_t r0 = (size_t)(blockIdx.x >> 4) * 128;
    const int c0 = (blockIdx.x & 15) * 128;

    // stationary WcT fragments + D fragments for this col-slice
    bf16x8 wb0[8], wb1[8];
    float4 dvv[8];
#pragma unroll
    for (int ct = 0; ct < 8; ++ct) {
        const ushort_t* p = WcT + (size_t)(c0 + ct * 16 + m16) * RK + quad * 8;
        wb0[ct] = *(const bf16x8*)(p);
        wb1[ct] = *(const bf16x8*)(p + 32);
        dvv[ct] = *(const float4*)(Dvec + c0 + ct * 16 + quad * 4);
    }

    for (int g = 0; g < 8; ++g) {
        const size_t rg = r0 + g * 16;
        const ushort_t* tp = tg + (rg + m16) * RK + quad * 8;
        bf16x8 ta0 = *(const bf16x8*)(tp);
        bf16x8 ta1 = *(const bf16x8*)(tp + 32);
        const float* up = u + (rg + m16) * DM + c0 + quad * 4;
        float* op = out + (rg + m16) * DM + c0 + quad * 4;
#pragma unroll
        for (int ct = 0; ct < 8; ++ct) {
            f32x4 o = {0.f, 0.f, 0.f, 0.f};
            // lane stores out[rg+m16][c0 + ct*16 + quad*4 + i]  -> float4
            o = __builtin_amdgcn_mfma_f32_16x16x32_bf16(wb0[ct], ta0, o, 0, 0, 0);
            o = __builtin_amdgcn_mfma_f32_16x16x32_bf16(wb1[ct], ta1, o, 0, 0, 0);
            float4 uv = *(const float4*)(up + ct * 16);
            f32x4 st;
            st[0] = o[0] + dvv[ct].x * uv.x;
            st[1] = o[1] + dvv[ct].y * uv.y;
            st[2] = o[2] + dvv[ct].z * uv.z;
            st[3] = o[3] + dvv[ct].w * uv.w;
            *(f32x4*)(op + ct * 16) = st;
        }
    }
}

extern "C" void kernel_launch(void* const* d_in, const int* in_sizes, int n_in,
                              void* d_out, int out_size, void* d_ws, size_t ws_size,
                              hipStream_t stream) {
    (void)in_sizes; (void)n_in; (void)out_size; (void)ws_size;
    const float* u   = (const float*)d_in[0];
    const float* Af  = (const float*)d_in[1];
    const float* Wbr = (const float*)d_in[2];
    const float* Wbs = (const float*)d_in[3];
    const float* Wcr = (const float*)d_in[4];
    const float* Wcm = (const float*)d_in[5];
    const float* Dv  = (const float*)d_in[6];
    float* out = (float*)d_out;

    char* ws = (char*)d_ws;
    float*    Mmid  = (float*)(ws + 0);            // 64*64*4    =   16384
    ushort_t* WeffT = (ushort_t*)(ws + 16384);     // 64*2048*2  =  262144
    ushort_t* WcT   = (ushort_t*)(ws + 278528);    // 2048*64*2  =  262144
    ushort_t* tg    = (ushort_t*)(ws + 540672);    // 16384*64*2 = 2097152

    k_p1<<<16, 256, 0, stream>>>(Wbs, Af, Wcr, Mmid);
    k_p2<<<64, 256, 0, stream>>>(Wbr, Mmid, Wcm, WeffT, WcT);
    k_a <<<256, 512, 0, stream>>>(u, WeffT, tg);
    k_b <<<2048, 64, 0, stream>>>(tg, u, WcT, Dv, out);
}

// Round 8
// 315.507 us; speedup vs baseline: 1.0844x; 1.0125x over previous
//
#include <hip/hip_runtime.h>

typedef unsigned short ushort_t;
typedef __attribute__((ext_vector_type(8))) short bf16x8;     // 8 bf16 (4 VGPRs)
typedef __attribute__((ext_vector_type(4))) float f32x4;
typedef __attribute__((ext_vector_type(4))) unsigned short us4;
typedef __attribute__((ext_vector_type(2))) unsigned short us2;

#define DM 2048
#define RK 64

__device__ __forceinline__ ushort_t f2b(float f) {
    union { float f; unsigned u; } x; x.f = f;
    unsigned r = x.u + 0x7fff + ((x.u >> 16) & 1);   // RNE
    return (ushort_t)(r >> 16);
}

// ---------------- P1: Mmid[64][64] = butterfly(Wbs) @ Wcr ----------------
__global__ void k_p1(const float* __restrict__ Wbs, const float* __restrict__ Af,
                     const float* __restrict__ Wcr, float* __restrict__ Mmid) {
    __shared__ float X[64 * 256];          // 64 KB, becomes T1
    const int tid = threadIdx.x;
#pragma unroll
    for (int i = 0; i < 16; ++i) {
        int e = (i * 256 + tid) * 4;
        *(float4*)&X[e] = *(const float4*)&Wbs[e];
    }
    __syncthreads();
#pragma unroll
    for (int l = 0; l < 8; ++l) {
        const int bit = 1 << (7 - l);
        const float a00 = Af[l * 4 + 0], a01 = Af[l * 4 + 1];
        const float a10 = Af[l * 4 + 2], a11 = Af[l * 4 + 3];
#pragma unroll 4
        for (int p = 0; p < 32; ++p) {
            int pid = p * 256 + tid;
            int row = pid >> 7;
            int off = pid & 127;
            int lo = off & (bit - 1);
            int n0 = ((off ^ lo) << 1) | lo;
            int n1 = n0 | bit;
            float x0 = X[row * 256 + n0], x1 = X[row * 256 + n1];
            X[row * 256 + n0] = x0 * a00 + x1 * a10;
            X[row * 256 + n1] = x0 * a01 + x1 * a11;
        }
        __syncthreads();
    }
    int g = blockIdx.x * 256 + tid;
    int r1 = g >> 6, r2 = g & 63;
    float s = 0.f;
#pragma unroll 8
    for (int n = 0; n < 256; ++n) s += X[r1 * 256 + n] * Wcr[n * 64 + r2];
    Mmid[g] = s;
}

// ---------------- P2: WeffT[64][2048] = (Wbr @ Mmid)^T, WcT[2048][64] = Wcm^T ----
__global__ void k_p2(const float* __restrict__ Wbr, const float* __restrict__ Mmid,
                     const float* __restrict__ Wcm,
                     ushort_t* __restrict__ WeffT, ushort_t* __restrict__ WcT) {
    const int b = blockIdx.x, tid = threadIdx.x;
    if (b < 32) {
        __shared__ float LW[64][65];
        __shared__ float LM[64 * 64];
#pragma unroll
        for (int i = 0; i < 4; ++i) {
            int e = (i * 256 + tid) * 4;
            int kk = e >> 6, r = e & 63;
            float4 v = *(const float4*)&Wbr[(size_t)b * 4096 + e];
            LW[kk][r] = v.x; LW[kk][r + 1] = v.y; LW[kk][r + 2] = v.z; LW[kk][r + 3] = v.w;
        }
#pragma unroll
        for (int i = 0; i < 4; ++i) {
            int e = (i * 256 + tid) * 4;
            *(float4*)&LM[e] = *(const float4*)&Mmid[e];
        }
        __syncthreads();
        int kk = tid & 63, n0 = (tid >> 6) * 16;
        float acc[16];
#pragma unroll
        for (int j = 0; j < 16; ++j) acc[j] = 0.f;
        for (int r = 0; r < 64; ++r) {
            float wv = LW[kk][r];
            const float* mrow = &LM[r * 64 + n0];
            float4 m0 = *(const float4*)(mrow);
            float4 m1 = *(const float4*)(mrow + 4);
            float4 m2 = *(const float4*)(mrow + 8);
            float4 m3 = *(const float4*)(mrow + 12);
            acc[0] += wv * m0.x; acc[1] += wv * m0.y; acc[2] += wv * m0.z; acc[3] += wv * m0.w;
            acc[4] += wv * m1.x; acc[5] += wv * m1.y; acc[6] += wv * m1.z; acc[7] += wv * m1.w;
            acc[8] += wv * m2.x; acc[9] += wv * m2.y; acc[10] += wv * m2.z; acc[11] += wv * m2.w;
            acc[12] += wv * m3.x; acc[13] += wv * m3.y; acc[14] += wv * m3.z; acc[15] += wv * m3.w;
        }
#pragma unroll
        for (int j = 0; j < 16; ++j)
            WeffT[(size_t)(n0 + j) * DM + b * 64 + kk] = f2b(acc[j]);
    } else {
        __shared__ float LT[64][65];
        const int n0 = (b - 32) * 64;
#pragma unroll
        for (int i = 0; i < 4; ++i) {
            int e = (i * 256 + tid) * 4;
            int k = e >> 6, nn = e & 63;
            float4 v = *(const float4*)&Wcm[(size_t)k * DM + n0 + nn];
            LT[k][nn] = v.x; LT[k][nn + 1] = v.y; LT[k][nn + 2] = v.z; LT[k][nn + 3] = v.w;
        }
        __syncthreads();
#pragma unroll
        for (int i = 0; i < 4; ++i) {
            int e = (i * 256 + tid) * 4;
            int nn = e >> 6, k = e & 63;
            us4 o;
            o.x = f2b(LT[k][nn]); o.y = f2b(LT[k + 1][nn]);
            o.z = f2b(LT[k + 2][nn]); o.w = f2b(LT[k + 3][nn]);
            *(us4*)&WcT[(size_t)(n0 + nn) * RK + k] = o;
        }
    }
}

// ---------------- fused main: out = (u @ W_eff) @ W_c_model + D*u ----------------
// 256 blocks x 8 waves x 64 rows (1 block/CU, no tail).
// Phase 1 (= verified R7 k_a): wave w pins WeffT K-slice [w*256,+256) x 64n in
// 32 bf16x8 register fragments loaded once; u streams from global into MFMAs;
// per 16-row group a cross-wave f32 LDS reduce writes t (bf16) into tsh
// (LDS, stride 72) instead of global -- no t round-trip.
// Phase 2 (= verified R7 k_b math): wave w owns out-cols [w*256,+256); t-frags
// from LDS, WcT frags from L2, u re-read is L3-warm (u fits the 256MB L3),
// float4 stores.
__global__ __launch_bounds__(512) void k_main(const float* __restrict__ u,
                                              const ushort_t* __restrict__ WeffT,
                                              const ushort_t* __restrict__ WcT,
                                              const float* __restrict__ Dvec,
                                              float* __restrict__ out) {
    __shared__ float red[8][64][20];       // 40 KB partial-t, [wave][n][r]
    __shared__ ushort_t tsh[64 * 72];      // 9 KB t bf16, [row][n] stride 72

    const int tid = threadIdx.x;
    const int w = tid >> 6;                // wave 0..7 -> K-slice [w*256,+256)
    const int lane = tid & 63;
    const int m16 = lane & 15;
    const int quad = lane >> 4;
    const size_t r0 = (size_t)blockIdx.x * 64;

    // ---- preload stationary weight fragments (32 x 16B, L2-resident) ----
    bf16x8 Wf[8][4];
    {
        const ushort_t* wbase = WeffT + (size_t)m16 * DM + w * 256 + quad * 8;
#pragma unroll
        for (int c = 0; c < 8; ++c)
#pragma unroll
            for (int j = 0; j < 4; ++j)
                Wf[c][j] = *(const bf16x8*)(wbase + (size_t)j * 16 * DM + c * 32);
    }

    // ---- phase 1: 4 groups of 16 rows ----
    for (int g = 0; g < 4; ++g) {
        const float* ap = u + (r0 + g * 16 + m16) * DM + w * 256 + quad * 8;
        f32x4 acc[4];
#pragma unroll
        for (int j = 0; j < 4; ++j) acc[j] = (f32x4){0.f, 0.f, 0.f, 0.f};

#pragma unroll
        for (int c = 0; c < 8; ++c) {
            float4 u0 = *(const float4*)(ap + c * 32);
            float4 u1 = *(const float4*)(ap + c * 32 + 4);
            bf16x8 a;
            a[0] = (short)f2b(u0.x); a[1] = (short)f2b(u0.y);
            a[2] = (short)f2b(u0.z); a[3] = (short)f2b(u0.w);
            a[4] = (short)f2b(u1.x); a[5] = (short)f2b(u1.y);
            a[6] = (short)f2b(u1.z); a[7] = (short)f2b(u1.w);
#pragma unroll
            for (int j = 0; j < 4; ++j)
                acc[j] = __builtin_amdgcn_mfma_f32_16x16x32_bf16(a, Wf[c][j], acc[j], 0, 0, 0);
        }

        // partial t: acc[j][i] = t[r = quad*4+i][n = 16j+m16]
#pragma unroll
        for (int j = 0; j < 4; ++j)
            *(f32x4*)&red[w][16 * j + m16][quad * 4] = acc[j];
        __syncthreads();

        // reduce 1024 entries / 512 threads = 2 each -> tsh (bf16, LDS)
        {
            const int r = tid >> 5;             // 0..15
            const int n0 = (tid & 31) * 2;      // 0..62 even
            float s0 = 0.f, s1 = 0.f;
#pragma unroll
            for (int ww = 0; ww < 8; ++ww) {
                s0 += red[ww][n0][r];
                s1 += red[ww][n0 + 1][r];
            }
            us2 o; o.x = f2b(s0); o.y = f2b(s1);
            *(us2*)&tsh[(g * 16 + r) * 72 + n0] = o;
        }
        __syncthreads();                        // red reusable; tsh visible
    }

    // ---- phase 2: wave w -> out-cols [w*256,+256) of all 64 rows ----
    bf16x8 ta0[4], ta1[4];
#pragma unroll
    for (int rg = 0; rg < 4; ++rg) {
        ta0[rg] = *(const bf16x8*)&tsh[(rg * 16 + m16) * 72 + quad * 8];
        ta1[rg] = *(const bf16x8*)&tsh[(rg * 16 + m16) * 72 + 32 + quad * 8];
    }
    const int cb = w * 256;
    const ushort_t* wcb = WcT + (size_t)(cb + m16) * RK + quad * 8;
    const float* up = u + (r0 + m16) * DM + cb + quad * 4;
    const float* dp = Dvec + cb + quad * 4;
    float* op = out + (r0 + m16) * DM + cb + quad * 4;

#pragma unroll 2
    for (int ct = 0; ct < 16; ++ct) {
        const ushort_t* p = wcb + (size_t)ct * 16 * RK;
        bf16x8 wb0 = *(const bf16x8*)(p);
        bf16x8 wb1 = *(const bf16x8*)(p + 32);
        float4 dv = *(const float4*)(dp + ct * 16);
#pragma unroll
        for (int rg = 0; rg < 4; ++rg) {
            f32x4 o = {0.f, 0.f, 0.f, 0.f};
            // lane stores out[r0 + rg*16 + m16][cb + ct*16 + quad*4 + i]
            o = __builtin_amdgcn_mfma_f32_16x16x32_bf16(wb0, ta0[rg], o, 0, 0, 0);
            o = __builtin_amdgcn_mfma_f32_16x16x32_bf16(wb1, ta1[rg], o, 0, 0, 0);
            float4 uv = *(const float4*)(up + (size_t)rg * 16 * DM + ct * 16);
            f32x4 st;
            st[0] = o[0] + dv.x * uv.x;
            st[1] = o[1] + dv.y * uv.y;
            st[2] = o[2] + dv.z * uv.z;
            st[3] = o[3] + dv.w * uv.w;
            *(f32x4*)(op + (size_t)rg * 16 * DM + ct * 16) = st;
        }
    }
}

extern "C" void kernel_launch(void* const* d_in, const int* in_sizes, int n_in,
                              void* d_out, int out_size, void* d_ws, size_t ws_size,
                              hipStream_t stream) {
    (void)in_sizes; (void)n_in; (void)out_size; (void)ws_size;
    const float* u   = (const float*)d_in[0];
    const float* Af  = (const float*)d_in[1];
    const float* Wbr = (const float*)d_in[2];
    const float* Wbs = (const float*)d_in[3];
    const float* Wcr = (const float*)d_in[4];
    const float* Wcm = (const float*)d_in[5];
    const float* Dv  = (const float*)d_in[6];
    float* out = (float*)d_out;

    char* ws = (char*)d_ws;
    float*    Mmid  = (float*)(ws + 0);            // 64*64*4    =   16384
    ushort_t* WeffT = (ushort_t*)(ws + 16384);     // 64*2048*2  =  262144
    ushort_t* WcT   = (ushort_t*)(ws + 278528);    // 2048*64*2  =  262144

    k_p1<<<16, 256, 0, stream>>>(Wbs, Af, Wcr, Mmid);
    k_p2<<<64, 256, 0, stream>>>(Wbr, Mmid, Wcm, WeffT, WcT);
    k_main<<<256, 512, 0, stream>>>(u, WeffT, WcT, Dv, out);
}